// Round 13
// baseline (570.838 us; speedup 1.0000x reference)
//
#include <hip/hip_runtime.h>
#include <math.h>

// Problem constants (fixed by setup_inputs)
#define NB 4
#define NS 4096
#define NL 8192
#define ND 256
#define NP2 128
#define NK 16

// Grid for spatial top-k pruning
#define GCELLS 32
#define GH 0.03125f     // 1/32, exact power of two
#define CAP 256         // per-wave candidate cap (overflow -> exact fallback)
#define EPSM 2e-5f      // skip margin >> 3e-6 total fp error of ref d2 chain

// ---------------------------------------------------------------------------
// Reference-matching fp32 distance metric (XLA/BLAS k=2 GEMM model) — VERIFIED
// on hardware through R12 (absmax 6.1e-5). DO NOT CHANGE THE BITS.
// ---------------------------------------------------------------------------
__device__ __forceinline__ float sum_sq_np(float x, float y) {
#pragma clang fp contract(off)
  return x * x + y * y;
}

__device__ __forceinline__ float dist2_fast(float q2, float m2, float qx, float qy,
                                            float mx, float my) {
#pragma clang fp contract(off)
  float dot = __builtin_fmaf(qy, my, qx * mx);
  float s = q2 + m2;
  return __builtin_fmaf(-2.0f, dot, s);
}

// float -> order-preserving uint (ascending float => ascending uint)
__device__ __forceinline__ unsigned f32ord(float f) {
  unsigned u = __float_as_uint(f);
  return u ^ ((unsigned)((int)u >> 31) | 0x80000000u);
}

// 16 rounds of wave-wide u64 min-extract over cand[0..cnt) (d2 asc, ties idx
// asc — exactly jax.lax.top_k's lower-index tie rule).
template <int NR>
__device__ __forceinline__ unsigned extract16(const unsigned long long* candrow,
                                              int cnt, int lane,
                                              int* __restrict__ outp) {
  unsigned long long myc[NR];
#pragma unroll
  for (int j = 0; j < NR; ++j) {
    int p = lane + j * 64;
    myc[j] = (p < cnt) ? candrow[p] : ~0ull;
  }
  unsigned tau_ord = 0xffffffffu;
#pragma unroll 1
  for (int r = 0; r < NK; ++r) {
    unsigned long long m = myc[0];
#pragma unroll
    for (int j = 1; j < NR; ++j) m = myc[j] < m ? myc[j] : m;
#pragma unroll
    for (int o = 1; o < 64; o <<= 1) {
      unsigned long long other = __shfl_xor(m, o, 64);
      if (other < m) m = other;
    }
    if (lane == 0) outp[r] = (int)(unsigned)(m & 0xffffffffull);
    if (r == NK - 1) tau_ord = (unsigned)(m >> 32);
#pragma unroll
    for (int j = 0; j < NR; ++j)
      if (myc[j] == m) myc[j] = ~0ull;
  }
  return tau_ord;
}

// ---------------------------------------------------------------------------
// Kernel 1 (R13): fused S+L MLP, 64 thr (1 wave), 16 rows, 4 cols/thread.
// R13 change: phase-3 r-SPLIT — h LDS holds only 8 rows at a time as
// h[256][12] (12.3 KB; stride 12 keeps float4 row alignment, 48-float lane
// stride on writes = 2-way alias = free, reads broadcast). LDS union drops
// 20.5 -> 12.3 KB => 13 blocks/CU (~3.25 waves/SIMD vs 2). Hidden stays in
// acc[16] regs across both halves; each half runs the FULL k=0..255 loop
// (W2 re-read is L2-warm). Each output row lives wholly in one half => its
// fmaf chain (k ascending, from bias) is IDENTICAL => bit-exact.
// NO min-waves clause (R8 spill lesson).
// ---------------------------------------------------------------------------
#define RPAD 20
#define HPAD 12
#define NSBLK (NB * NS / 16)  // 1024 S-instance blocks; total 3072

struct __align__(16) MlpSmem {
  union {
    float pe[NP2][RPAD];  // 10.24 KB, live phase1 -> end of phase2 k-loop
    float h[ND][HPAD];    // 12.29 KB, 8 rows per half, live in phase 3
  };
};

__device__ __forceinline__ void fma4row(float4& a, float p, const float4& w) {
  a.x = fmaf(p, w.x, a.x);
  a.y = fmaf(p, w.y, a.y);
  a.z = fmaf(p, w.z, a.z);
  a.w = fmaf(p, w.w, a.w);
}

// phase-2 consumer: 4 k-steps, per k read pe row (16 floats, broadcast),
// 16x4 FMAs.
__device__ __forceinline__ void consume4v(const float (*L)[RPAD], int k0,
                                          const float4* w, float4* acc) {
#pragma unroll
  for (int u = 0; u < 4; ++u) {
    int k = k0 + u;
    float4 p0 = *(const float4*)&L[k][0];
    float4 p1 = *(const float4*)&L[k][4];
    float4 p2 = *(const float4*)&L[k][8];
    float4 p3 = *(const float4*)&L[k][12];
    float4 wu = w[u];
    fma4row(acc[0],  p0.x, wu); fma4row(acc[1],  p0.y, wu);
    fma4row(acc[2],  p0.z, wu); fma4row(acc[3],  p0.w, wu);
    fma4row(acc[4],  p1.x, wu); fma4row(acc[5],  p1.y, wu);
    fma4row(acc[6],  p1.z, wu); fma4row(acc[7],  p1.w, wu);
    fma4row(acc[8],  p2.x, wu); fma4row(acc[9],  p2.y, wu);
    fma4row(acc[10], p2.z, wu); fma4row(acc[11], p2.w, wu);
    fma4row(acc[12], p3.x, wu); fma4row(acc[13], p3.y, wu);
    fma4row(acc[14], p3.z, wu); fma4row(acc[15], p3.w, wu);
  }
}

// phase-3 consumer: 4 k-steps, per k read h row (8 floats, broadcast),
// 8x4 FMAs.
__device__ __forceinline__ void consume4h(const float (*H)[HPAD], int k0,
                                          const float4* w, float4* out8) {
#pragma unroll
  for (int u = 0; u < 4; ++u) {
    int k = k0 + u;
    float4 p0 = *(const float4*)&H[k][0];
    float4 p1 = *(const float4*)&H[k][4];
    float4 wu = w[u];
    fma4row(out8[0], p0.x, wu); fma4row(out8[1], p0.y, wu);
    fma4row(out8[2], p0.z, wu); fma4row(out8[3], p0.w, wu);
    fma4row(out8[4], p1.x, wu); fma4row(out8[5], p1.y, wu);
    fma4row(out8[6], p1.z, wu); fma4row(out8[7], p1.w, wu);
  }
}

__global__ __launch_bounds__(64) void mlp_fused_kernel(
    const float* __restrict__ q_coor, const float* __restrict__ mem_coor,
    const float* __restrict__ memory,
    const float* __restrict__ Wq1, const float* __restrict__ bq1,
    const float* __restrict__ Wq2, const float* __restrict__ bq2,
    const float* __restrict__ Wk1, const float* __restrict__ bk1,
    const float* __restrict__ Wk2, const float* __restrict__ bk2,
    float* __restrict__ query, float* __restrict__ kv_pe) {
  __shared__ MlpSmem sm;
  const int tid = threadIdx.x;   // 0..63
  const int bid = blockIdx.x;
  const bool isS = bid < NSBLK;
  const float* coor = isS ? q_coor : mem_coor;
  const float* W1 = isS ? Wq1 : Wk1;
  const float* b1 = isS ? bq1 : bk1;
  const float* W2 = isS ? Wq2 : Wk2;
  const float* b2 = isS ? bq2 : bk2;
  const float* addmem = isS ? (const float*)nullptr : memory;
  float* out = isS ? query : kv_pe;
  const int row0 = (isS ? bid : bid - NSBLK) * 16;
  const int c0 = tid * 4;

  // ---- phase 1: PETR 2D sine embedding, transposed into LDS ----
#pragma unroll
  for (int it = 0; it < 16; ++it) {
    int e = tid + it * 64;      // 0..1023 = 16 rows * 2 parts * 32 j
    int r = e >> 6;
    int rem = e & 63;
    int part = rem >> 5;        // 0 -> y, 1 -> x
    int j = rem & 31;
    float c = coor[(size_t)(row0 + r) * 2 + (part ^ 1)];
    float inv_t = exp2f((float)j * -0.4152410118609718f);  // 10000^(-j/32)
    float arg = c * 6.2831853071795864f * inv_t;
    float sv, cv;
    sincosf(arg, &sv, &cv);
    int k0 = part * 64 + 2 * j;
    sm.pe[k0][r] = sv;
    sm.pe[k0 + 1][r] = cv;
  }
  __syncthreads();

  // ---- phase 2: hidden = relu(pe @ W1 + b1) -> acc regs (pre-relu) ----
  float4 acc[16];
  float4 wA[4], wB[4];
  {
    float4 bb = *(const float4*)&b1[c0];
#pragma unroll
    for (int r = 0; r < 16; ++r) acc[r] = bb;
  }
#pragma unroll
  for (int u = 0; u < 4; ++u)
    wA[u] = *(const float4*)&W1[(size_t)u * ND + c0];
#pragma unroll 1
  for (int k0 = 0; k0 < NP2; k0 += 8) {
#pragma unroll
    for (int u = 0; u < 4; ++u)
      wB[u] = *(const float4*)&W1[(size_t)(k0 + 4 + u) * ND + c0];
    consume4v(sm.pe, k0, wA, acc);
    if (k0 + 8 < NP2) {
#pragma unroll
      for (int u = 0; u < 4; ++u)
        wA[u] = *(const float4*)&W1[(size_t)(k0 + 8 + u) * ND + c0];
    }
    consume4v(sm.pe, k0 + 4, wB, acc);
  }

  // ---- phase 3: out = relu(hidden) @ W2 + b2 (+ memory), r-split halves --
  float4 out8[8];
  const float4 bb2 = *(const float4*)&b2[c0];
#pragma unroll 1
  for (int half = 0; half < 2; ++half) {
    const int r0 = half * 8;
    // barrier: half0 -> pe reads done before h overwrites union;
    // half1 -> half0's h reads done before overwrite.
    __syncthreads();
#pragma unroll
    for (int i = 0; i < 8; ++i) {
      float4 a = acc[r0 + i];
      sm.h[c0 + 0][i] = fmaxf(a.x, 0.0f);
      sm.h[c0 + 1][i] = fmaxf(a.y, 0.0f);
      sm.h[c0 + 2][i] = fmaxf(a.z, 0.0f);
      sm.h[c0 + 3][i] = fmaxf(a.w, 0.0f);
    }
    __syncthreads();
#pragma unroll
    for (int i = 0; i < 8; ++i) out8[i] = bb2;
#pragma unroll
    for (int u = 0; u < 4; ++u)
      wA[u] = *(const float4*)&W2[(size_t)u * ND + c0];
#pragma unroll 1
    for (int k0 = 0; k0 < ND; k0 += 8) {
#pragma unroll
      for (int u = 0; u < 4; ++u)
        wB[u] = *(const float4*)&W2[(size_t)(k0 + 4 + u) * ND + c0];
      consume4h(sm.h, k0, wA, out8);
      if (k0 + 8 < ND) {
#pragma unroll
        for (int u = 0; u < 4; ++u)
          wA[u] = *(const float4*)&W2[(size_t)(k0 + 8 + u) * ND + c0];
      }
      consume4h(sm.h, k0 + 4, wB, out8);
    }
#pragma unroll
    for (int i = 0; i < 8; ++i) {
      size_t g = (size_t)(row0 + r0 + i);
      float4 v = out8[i];
      if (addmem) {
        float4 mm = *(const float4*)&addmem[g * ND + c0];
        v.x += mm.x; v.y += mm.y; v.z += mm.z; v.w += mm.w;
      }
      *(float4*)&out[g * ND + c0] = v;
    }
  }
}

// ---------------------------------------------------------------------------
// Kernel 2a: fused build. Blocks [0,NB): counting-sort mem points into cell
// order (sorted records + starts). Blocks [NB,2*NB): counting-sort the
// QUERIES by cell -> qord, used by attn for gather locality. (verified)
// ---------------------------------------------------------------------------
__global__ __launch_bounds__(1024) void build_kernel(
    const float* __restrict__ mem_coor, const float* __restrict__ q_coor,
    float4* __restrict__ sorted, int* __restrict__ starts,
    int* __restrict__ qord) {
  __shared__ int hist[GCELLS * GCELLS];
  __shared__ int cur[GCELLS * GCELLS];
  const int bid = blockIdx.x;
  const bool isMem = bid < NB;
  const int b = isMem ? bid : bid - NB;
  const int n = isMem ? NL : NS;
  const float2* cc = (const float2*)(isMem ? mem_coor : q_coor) + (size_t)b * n;
  const int tid = threadIdx.x;

  hist[tid] = 0;
  __syncthreads();
  for (int it = 0; it < n / 1024; ++it) {
    float2 c = cc[it * 1024 + tid];
    int cx = (int)(c.x * 32.0f); cx = cx > 31 ? 31 : cx;
    int cy = (int)(c.y * 32.0f); cy = cy > 31 ? 31 : cy;
    atomicAdd(&hist[cy * GCELLS + cx], 1);
  }
  __syncthreads();
  const int own = hist[tid];
  for (int o = 1; o < 1024; o <<= 1) {
    int v = (tid >= o) ? hist[tid - o] : 0;
    __syncthreads();
    hist[tid] += v;
    __syncthreads();
  }
  const int excl = hist[tid] - own;
  if (isMem) {
    starts[b * (GCELLS * GCELLS + 1) + tid] = excl;
    if (tid == 0) starts[b * (GCELLS * GCELLS + 1) + GCELLS * GCELLS] = NL;
  }
  cur[tid] = excl;
  __syncthreads();
  for (int it = 0; it < n / 1024; ++it) {
    int i = it * 1024 + tid;
    float2 c = cc[i];
    int cx = (int)(c.x * 32.0f); cx = cx > 31 ? 31 : cx;
    int cy = (int)(c.y * 32.0f); cy = cy > 31 ? 31 : cy;
    int pos = atomicAdd(&cur[cy * GCELLS + cx], 1);
    if (isMem) {
      sorted[(size_t)b * NL + pos] =
          make_float4(c.x, c.y, sum_sq_np(c.x, c.y), __int_as_float(i));
    } else {
      qord[b * NS + pos] = i;
    }
  }
}

// ---------------------------------------------------------------------------
// Kernel 2b: grid-pruned exact top-16 (R9-verified 4-wave form). One wave per
// query; ring-growing bound check; exact full-scan fallback on candidate
// overflow. (verified on hardware: absmax 6.1e-5)
// ---------------------------------------------------------------------------
__global__ __launch_bounds__(256) void topk_kernel(
    const float* __restrict__ q_coor, const float4* __restrict__ sorted,
    const int* __restrict__ starts, int* __restrict__ idx_out) {
  __shared__ unsigned long long cand[4][CAP];  // 8 KB
  __shared__ int fcnt[4];

  const int tid = threadIdx.x;
  const int wv = tid >> 6;
  const int lane = tid & 63;
  const int qi = blockIdx.x * 4 + wv;  // b*S + s
  const int b = qi >> 12;              // / NS

  const float qx = q_coor[(size_t)qi * 2 + 0];
  const float qy = q_coor[(size_t)qi * 2 + 1];
  const float q2 = sum_sq_np(qx, qy);
  const float4* sp = sorted + (size_t)b * NL;
  const int* st = starts + b * (GCELLS * GCELLS + 1);
  int* outp = idx_out + (size_t)qi * NK;

  int ci = (int)(qx * 32.0f); ci = ci > 31 ? 31 : ci;
  int cj = (int)(qy * 32.0f); cj = cj > 31 ? 31 : cj;

  int x0 = ci - 1 < 0 ? 0 : ci - 1, x1 = ci + 1 > 31 ? 31 : ci + 1;
  int y0 = cj - 1 < 0 ? 0 : cj - 1, y1 = cj + 1 > 31 ? 31 : cj + 1;
  int cnt = 0;
  bool ovf = false;

  auto span = [&](int y, int xa, int xb) {
    int s0 = st[y * GCELLS + xa];
    int e0 = st[y * GCELLS + xb + 1];
    int len = e0 - s0;
    if (cnt + len > CAP) { ovf = true; return; }
    for (int i = lane; i < len; i += 64) {
      float4 rx = sp[s0 + i];
      float d2 = dist2_fast(q2, rx.z, qx, qy, rx.x, rx.y);
      cand[wv][cnt + i] = ((unsigned long long)f32ord(d2) << 32) |
                          (unsigned)__float_as_int(rx.w);
    }
    cnt += len;
  };

  for (int y = y0; y <= y1 && !ovf; ++y) span(y, x0, x1);

  int R = 1;
  while (!ovf) {
    unsigned tau_ord;
    if (cnt <= 128) tau_ord = extract16<2>(cand[wv], cnt, lane, outp);
    else            tau_ord = extract16<4>(cand[wv], cnt, lane, outp);
    float dxl = x0 > 0  ? qx - (float)x0 * GH        : 1e30f;
    float dxr = x1 < 31 ? (float)(x1 + 1) * GH - qx  : 1e30f;
    float dyl = y0 > 0  ? qy - (float)y0 * GH        : 1e30f;
    float dyr = y1 < 31 ? (float)(y1 + 1) * GH - qy  : 1e30f;
    float dmin = fminf(fminf(dxl, dxr), fminf(dyl, dyr));
    float bound = dmin * dmin - EPSM;
    if (cnt >= NK && tau_ord < f32ord(bound)) return;
    if (x0 == 0 && x1 == 31 && y0 == 0 && y1 == 31) return;  // all visited
    ++R;
    int nx0 = ci - R < 0 ? 0 : ci - R, nx1 = ci + R > 31 ? 31 : ci + R;
    int ny0 = cj - R < 0 ? 0 : cj - R, ny1 = cj + R > 31 ? 31 : cj + R;
    if (ny0 < y0) span(ny0, nx0, nx1);
    if (ny1 > y1 && !ovf) span(ny1, nx0, nx1);
    for (int y = y0; y <= y1 && !ovf; ++y) {
      if (nx0 < x0) span(y, nx0, x0 - 1);
      if (nx1 > x1 && !ovf) span(y, x1 + 1, nx1);
    }
    x0 = nx0; x1 = nx1; y0 = ny0; y1 = ny1;
  }

  // ---- exact fallback: full scan over sorted records ----
  float lmin = __builtin_inff();
#pragma unroll 8
  for (int it = 0; it < NL / 64; ++it) {
    float4 rx = sp[it * 64 + lane];
    float d2 = dist2_fast(q2, rx.z, qx, qy, rx.x, rx.y);
    lmin = fminf(lmin, d2);
  }
  float tau;
  {
    float curm = lmin;
    for (int r = 0; r < NK; ++r) {
      float m = curm;
#pragma unroll
      for (int o = 1; o < 64; o <<= 1) m = fminf(m, __shfl_xor(m, o, 64));
      tau = m;
      if (curm == m) curm = __builtin_inff();
    }
  }
  if (lane == 0) fcnt[wv] = 0;
#pragma unroll 4
  for (int it = 0; it < NL / 64; ++it) {
    float4 rx = sp[it * 64 + lane];
    float d2 = dist2_fast(q2, rx.z, qx, qy, rx.x, rx.y);
    bool hit = (d2 <= tau);
    unsigned long long mask = __ballot(hit);
    if (mask) {
      int base = fcnt[wv];
      if (hit) {
        int pos = base + (int)__popcll(mask & ((1ull << lane) - 1ull));
        if (pos < CAP) {
          cand[wv][pos] = ((unsigned long long)f32ord(d2) << 32) |
                          (unsigned)__float_as_int(rx.w);
        }
      }
      if (lane == 0) fcnt[wv] = base + (int)__popcll(mask);
    }
  }
  int N = fcnt[wv];
  if (N > CAP) N = CAP;
  extract16<4>(cand[wv], N, lane, outp);
}

// ---------------------------------------------------------------------------
// Kernel 3: gather + per-(b,s,k) softmax over D + scale by memory.
// One wave per (b,s); cell-sorted query order (qord) + XCD swizzle for L2
// gather locality (verified R9: ~-35 us vs unsorted). Bit-identical for any
// permutation.
// ---------------------------------------------------------------------------
__global__ __launch_bounds__(256) void attn_kernel(
    const float* __restrict__ query, const float* __restrict__ kv_pe,
    const float* __restrict__ memory, const int* __restrict__ idx,
    const int* __restrict__ qord, float* __restrict__ out) {
  const int tid = threadIdx.x;
  const int wv = tid >> 6;
  const int lane = tid & 63;
  // XCD swizzle: 4096 blocks, bijective (4096 % 8 == 0)
  const int bid = ((blockIdx.x & 7) * (NB * NS / 4 / 8)) + (blockIdx.x >> 3);
  const int qpos = bid * 4 + wv;       // position in sorted order
  const int b = qpos >> 12;            // / NS
  const int qi = b * NS + qord[qpos];  // original b*S + s

  float4 q4 = *(const float4*)(query + (size_t)qi * ND + lane * 4);
  int lv = 0;
  if (lane < NK) lv = idx[(size_t)qi * NK + lane];

#pragma unroll 4
  for (int k = 0; k < NK; ++k) {
    int l = __shfl(lv, k, 64);
    size_t base = ((size_t)b * NL + l) * ND + (size_t)lane * 4;
    float4 kv = *(const float4*)(kv_pe + base);
    float4 mm = *(const float4*)(memory + base);
    // prod = query * kv_pe / sqrt(256); /16 is exact so *0.0625f matches bits
    float p0 = q4.x * kv.x * 0.0625f;
    float p1 = q4.y * kv.y * 0.0625f;
    float p2 = q4.z * kv.z * 0.0625f;
    float p3 = q4.w * kv.w * 0.0625f;
    float mx = fmaxf(fmaxf(p0, p1), fmaxf(p2, p3));
#pragma unroll
    for (int o = 1; o < 64; o <<= 1) mx = fmaxf(mx, __shfl_xor(mx, o, 64));
    float e0 = expf(p0 - mx);
    float e1 = expf(p1 - mx);
    float e2 = expf(p2 - mx);
    float e3 = expf(p3 - mx);
    float s = (e0 + e1) + (e2 + e3);
#pragma unroll
    for (int o = 1; o < 64; o <<= 1) s += __shfl_xor(s, o, 64);
    float inv = 1.0f / s;
    float4 o4;
    o4.x = e0 * inv * mm.x;
    o4.y = e1 * inv * mm.y;
    o4.z = e2 * inv * mm.z;
    o4.w = e3 * inv * mm.w;
    *(float4*)(out + ((size_t)qi * NK + k) * ND + (size_t)lane * 4) = o4;
  }
}

// ---------------------------------------------------------------------------
extern "C" void kernel_launch(void* const* d_in, const int* in_sizes, int n_in,
                              void* d_out, int out_size, void* d_ws, size_t ws_size,
                              hipStream_t stream) {
  (void)in_sizes; (void)n_in; (void)out_size; (void)ws_size;
  const float* memory   = (const float*)d_in[0];
  const float* mem_coor = (const float*)d_in[1];
  const float* q_coor   = (const float*)d_in[2];
  const float* Wq1 = (const float*)d_in[3];
  const float* bq1 = (const float*)d_in[4];
  const float* Wq2 = (const float*)d_in[5];
  const float* bq2 = (const float*)d_in[6];
  const float* Wk1 = (const float*)d_in[7];
  const float* bk1 = (const float*)d_in[8];
  const float* Wk2 = (const float*)d_in[9];
  const float* bk2 = (const float*)d_in[10];

  // workspace: query (16.8 MB) | kv_pe (33.6 MB) | idx (1 MB) | qord (64 KB)
  float* query = (float*)d_ws;
  float* kv_pe = query + (size_t)NB * NS * ND;
  int*   nidx  = (int*)(kv_pe + (size_t)NB * NL * ND);
  int*   qord  = nidx + (size_t)NB * NS * NK;
  float* outp  = (float*)d_out;

  // grid scratch lives in d_out (268 MB): consumed by topk (stream-ordered
  // before attn overwrites the buffer). qord lives in d_ws (attn reads it
  // while writing out).
  float4* sorted  = (float4*)d_out;                                  // 512 KB
  int*    gstarts = (int*)((char*)d_out + (size_t)NB * NL * 16);     // 16.4 KB

  hipLaunchKernelGGL(build_kernel, dim3(2 * NB), dim3(1024), 0, stream,
                     mem_coor, q_coor, sorted, gstarts, qord);
  hipLaunchKernelGGL(mlp_fused_kernel, dim3(NSBLK + NB * NL / 16), dim3(64),
                     0, stream, q_coor, mem_coor, memory,
                     Wq1, bq1, Wq2, bq2, Wk1, bk1, Wk2, bk2, query, kv_pe);
  hipLaunchKernelGGL(topk_kernel, dim3(NB * NS / 4), dim3(256), 0, stream,
                     q_coor, sorted, gstarts, nidx);
  hipLaunchKernelGGL(attn_kernel, dim3(NB * NS / 4), dim3(256), 0, stream,
                     query, kv_pe, memory, nidx, qord, outp);
}

// Round 14
// 526.597 us; speedup vs baseline: 1.0840x; 1.0840x over previous
//
#include <hip/hip_runtime.h>
#include <math.h>

// Problem constants (fixed by setup_inputs)
#define NB 4
#define NS 4096
#define NL 8192
#define ND 256
#define NP2 128
#define NK 16

// Grid for spatial top-k pruning
#define GCELLS 32
#define GH 0.03125f     // 1/32, exact power of two
#define CAP 256         // per-wave candidate cap (overflow -> exact fallback)
#define EPSM 2e-5f      // skip margin >> 3e-6 total fp error of ref d2 chain

// ---------------------------------------------------------------------------
// Reference-matching fp32 distance metric (XLA/BLAS k=2 GEMM model) — VERIFIED
// on hardware through R12 (absmax 6.1e-5). DO NOT CHANGE THE BITS.
// ---------------------------------------------------------------------------
__device__ __forceinline__ float sum_sq_np(float x, float y) {
#pragma clang fp contract(off)
  return x * x + y * y;
}

__device__ __forceinline__ float dist2_fast(float q2, float m2, float qx, float qy,
                                            float mx, float my) {
#pragma clang fp contract(off)
  float dot = __builtin_fmaf(qy, my, qx * mx);
  float s = q2 + m2;
  return __builtin_fmaf(-2.0f, dot, s);
}

// float -> order-preserving uint (ascending float => ascending uint)
__device__ __forceinline__ unsigned f32ord(float f) {
  unsigned u = __float_as_uint(f);
  return u ^ ((unsigned)((int)u >> 31) | 0x80000000u);
}

// 16 rounds of wave-wide u64 min-extract over cand[0..cnt) (d2 asc, ties idx
// asc — exactly jax.lax.top_k's lower-index tie rule).
template <int NR>
__device__ __forceinline__ unsigned extract16(const unsigned long long* candrow,
                                              int cnt, int lane,
                                              int* __restrict__ outp) {
  unsigned long long myc[NR];
#pragma unroll
  for (int j = 0; j < NR; ++j) {
    int p = lane + j * 64;
    myc[j] = (p < cnt) ? candrow[p] : ~0ull;
  }
  unsigned tau_ord = 0xffffffffu;
#pragma unroll 1
  for (int r = 0; r < NK; ++r) {
    unsigned long long m = myc[0];
#pragma unroll
    for (int j = 1; j < NR; ++j) m = myc[j] < m ? myc[j] : m;
#pragma unroll
    for (int o = 1; o < 64; o <<= 1) {
      unsigned long long other = __shfl_xor(m, o, 64);
      if (other < m) m = other;
    }
    if (lane == 0) outp[r] = (int)(unsigned)(m & 0xffffffffull);
    if (r == NK - 1) tau_ord = (unsigned)(m >> 32);
#pragma unroll
    for (int j = 0; j < NR; ++j)
      if (myc[j] == m) myc[j] = ~0ull;
  }
  return tau_ord;
}

// ---------------------------------------------------------------------------
// Kernel 1 (R12-verified, reverted from R13): fused S+L MLP, 64 thr (1 wave),
// 16 rows/block, FOUR cols per thread (c0 = 4*tid). FMA:LDS-read ratio 16:1;
// W loads/stores float4 coalesced. pe/h LDS union (20480 B). NO min-waves
// clause (R8 spill lesson); NO r-split (R13 lesson: +37 us from W2 re-read +
// L2 thrash; LDS size does NOT move this kernel's occupancy — measured
// pinned ~18-20% across 12.3/20.5/30.7 KB). Hardware result: 152 us class,
// bit-exact (absmax 6.1e-5).
// ---------------------------------------------------------------------------
#define RPAD 20
#define NSBLK (NB * NS / 16)  // 1024 S-instance blocks; total 3072

struct __align__(16) MlpSmem {
  union {
    float pe[NP2][RPAD];  // 10.24 KB, live phase1 -> end of phase2 k-loop
    float h[ND][RPAD];    // 20.48 KB, live after barrier -> end of phase3
  };
};

__device__ __forceinline__ void fma4row(float4& a, float p, const float4& w) {
  a.x = fmaf(p, w.x, a.x);
  a.y = fmaf(p, w.y, a.y);
  a.z = fmaf(p, w.z, a.z);
  a.w = fmaf(p, w.w, a.w);
}

// 4 k-steps: per k, read pe/h row (16 floats, broadcast) and do 16x4 FMAs.
__device__ __forceinline__ void consume4v(const float (*L)[RPAD], int k0,
                                          const float4* w, float4* acc) {
#pragma unroll
  for (int u = 0; u < 4; ++u) {
    int k = k0 + u;
    float4 p0 = *(const float4*)&L[k][0];
    float4 p1 = *(const float4*)&L[k][4];
    float4 p2 = *(const float4*)&L[k][8];
    float4 p3 = *(const float4*)&L[k][12];
    float4 wu = w[u];
    fma4row(acc[0],  p0.x, wu); fma4row(acc[1],  p0.y, wu);
    fma4row(acc[2],  p0.z, wu); fma4row(acc[3],  p0.w, wu);
    fma4row(acc[4],  p1.x, wu); fma4row(acc[5],  p1.y, wu);
    fma4row(acc[6],  p1.z, wu); fma4row(acc[7],  p1.w, wu);
    fma4row(acc[8],  p2.x, wu); fma4row(acc[9],  p2.y, wu);
    fma4row(acc[10], p2.z, wu); fma4row(acc[11], p2.w, wu);
    fma4row(acc[12], p3.x, wu); fma4row(acc[13], p3.y, wu);
    fma4row(acc[14], p3.z, wu); fma4row(acc[15], p3.w, wu);
  }
}

__global__ __launch_bounds__(64) void mlp_fused_kernel(
    const float* __restrict__ q_coor, const float* __restrict__ mem_coor,
    const float* __restrict__ memory,
    const float* __restrict__ Wq1, const float* __restrict__ bq1,
    const float* __restrict__ Wq2, const float* __restrict__ bq2,
    const float* __restrict__ Wk1, const float* __restrict__ bk1,
    const float* __restrict__ Wk2, const float* __restrict__ bk2,
    float* __restrict__ query, float* __restrict__ kv_pe) {
  __shared__ MlpSmem sm;
  const int tid = threadIdx.x;   // 0..63
  const int bid = blockIdx.x;
  const bool isS = bid < NSBLK;
  const float* coor = isS ? q_coor : mem_coor;
  const float* W1 = isS ? Wq1 : Wk1;
  const float* b1 = isS ? bq1 : bk1;
  const float* W2 = isS ? Wq2 : Wk2;
  const float* b2 = isS ? bq2 : bk2;
  const float* addmem = isS ? (const float*)nullptr : memory;
  float* out = isS ? query : kv_pe;
  const int row0 = (isS ? bid : bid - NSBLK) * 16;
  const int c0 = tid * 4;

  // ---- phase 1: PETR 2D sine embedding, transposed into LDS ----
#pragma unroll
  for (int it = 0; it < 16; ++it) {
    int e = tid + it * 64;      // 0..1023 = 16 rows * 2 parts * 32 j
    int r = e >> 6;
    int rem = e & 63;
    int part = rem >> 5;        // 0 -> y, 1 -> x
    int j = rem & 31;
    float c = coor[(size_t)(row0 + r) * 2 + (part ^ 1)];
    float inv_t = exp2f((float)j * -0.4152410118609718f);  // 10000^(-j/32)
    float arg = c * 6.2831853071795864f * inv_t;
    float sv, cv;
    sincosf(arg, &sv, &cv);
    int k0 = part * 64 + 2 * j;
    sm.pe[k0][r] = sv;
    sm.pe[k0 + 1][r] = cv;
  }
  __syncthreads();

  // ---- phase 2: hidden = relu(pe @ W1 + b1), 4-deep double-buffered W ----
  float4 acc[16];
  float4 wA[4], wB[4];
  {
    float4 bb = *(const float4*)&b1[c0];
#pragma unroll
    for (int r = 0; r < 16; ++r) acc[r] = bb;
  }
#pragma unroll
  for (int u = 0; u < 4; ++u)
    wA[u] = *(const float4*)&W1[(size_t)u * ND + c0];
#pragma unroll 1
  for (int k0 = 0; k0 < NP2; k0 += 8) {
#pragma unroll
    for (int u = 0; u < 4; ++u)
      wB[u] = *(const float4*)&W1[(size_t)(k0 + 4 + u) * ND + c0];
    consume4v(sm.pe, k0, wA, acc);
    if (k0 + 8 < NP2) {
#pragma unroll
      for (int u = 0; u < 4; ++u)
        wA[u] = *(const float4*)&W1[(size_t)(k0 + 8 + u) * ND + c0];
    }
    consume4v(sm.pe, k0 + 4, wB, acc);
  }
  __syncthreads();  // all pe reads complete before h overwrites union
  // thread owns hidden cols c0..c0+3: h[c][r] = relu(acc[r].comp(c-c0))
#pragma unroll
  for (int r = 0; r < 16; ++r) {
    sm.h[c0 + 0][r] = fmaxf(acc[r].x, 0.0f);
    sm.h[c0 + 1][r] = fmaxf(acc[r].y, 0.0f);
    sm.h[c0 + 2][r] = fmaxf(acc[r].z, 0.0f);
    sm.h[c0 + 3][r] = fmaxf(acc[r].w, 0.0f);
  }
  __syncthreads();

  // ---- phase 3: out = h @ W2 + b2 (+ memory), same structure, K=256 ----
  {
    float4 bb = *(const float4*)&b2[c0];
#pragma unroll
    for (int r = 0; r < 16; ++r) acc[r] = bb;
  }
#pragma unroll
  for (int u = 0; u < 4; ++u)
    wA[u] = *(const float4*)&W2[(size_t)u * ND + c0];
#pragma unroll 1
  for (int k0 = 0; k0 < ND; k0 += 8) {
#pragma unroll
    for (int u = 0; u < 4; ++u)
      wB[u] = *(const float4*)&W2[(size_t)(k0 + 4 + u) * ND + c0];
    consume4v(sm.h, k0, wA, acc);
    if (k0 + 8 < ND) {
#pragma unroll
      for (int u = 0; u < 4; ++u)
        wA[u] = *(const float4*)&W2[(size_t)(k0 + 8 + u) * ND + c0];
    }
    consume4v(sm.h, k0 + 4, wB, acc);
  }
#pragma unroll
  for (int r = 0; r < 16; ++r) {
    size_t g = (size_t)(row0 + r);
    float4 v = acc[r];
    if (addmem) {
      float4 mm = *(const float4*)&addmem[g * ND + c0];
      v.x += mm.x; v.y += mm.y; v.z += mm.z; v.w += mm.w;
    }
    *(float4*)&out[g * ND + c0] = v;
  }
}

// ---------------------------------------------------------------------------
// Kernel 2a: fused build. Blocks [0,NB): counting-sort mem points into cell
// order (sorted records + starts). Blocks [NB,2*NB): counting-sort the
// QUERIES by cell -> qord, used by attn for gather locality. (verified)
// ---------------------------------------------------------------------------
__global__ __launch_bounds__(1024) void build_kernel(
    const float* __restrict__ mem_coor, const float* __restrict__ q_coor,
    float4* __restrict__ sorted, int* __restrict__ starts,
    int* __restrict__ qord) {
  __shared__ int hist[GCELLS * GCELLS];
  __shared__ int cur[GCELLS * GCELLS];
  const int bid = blockIdx.x;
  const bool isMem = bid < NB;
  const int b = isMem ? bid : bid - NB;
  const int n = isMem ? NL : NS;
  const float2* cc = (const float2*)(isMem ? mem_coor : q_coor) + (size_t)b * n;
  const int tid = threadIdx.x;

  hist[tid] = 0;
  __syncthreads();
  for (int it = 0; it < n / 1024; ++it) {
    float2 c = cc[it * 1024 + tid];
    int cx = (int)(c.x * 32.0f); cx = cx > 31 ? 31 : cx;
    int cy = (int)(c.y * 32.0f); cy = cy > 31 ? 31 : cy;
    atomicAdd(&hist[cy * GCELLS + cx], 1);
  }
  __syncthreads();
  const int own = hist[tid];
  for (int o = 1; o < 1024; o <<= 1) {
    int v = (tid >= o) ? hist[tid - o] : 0;
    __syncthreads();
    hist[tid] += v;
    __syncthreads();
  }
  const int excl = hist[tid] - own;
  if (isMem) {
    starts[b * (GCELLS * GCELLS + 1) + tid] = excl;
    if (tid == 0) starts[b * (GCELLS * GCELLS + 1) + GCELLS * GCELLS] = NL;
  }
  cur[tid] = excl;
  __syncthreads();
  for (int it = 0; it < n / 1024; ++it) {
    int i = it * 1024 + tid;
    float2 c = cc[i];
    int cx = (int)(c.x * 32.0f); cx = cx > 31 ? 31 : cx;
    int cy = (int)(c.y * 32.0f); cy = cy > 31 ? 31 : cy;
    int pos = atomicAdd(&cur[cy * GCELLS + cx], 1);
    if (isMem) {
      sorted[(size_t)b * NL + pos] =
          make_float4(c.x, c.y, sum_sq_np(c.x, c.y), __int_as_float(i));
    } else {
      qord[b * NS + pos] = i;
    }
  }
}

// ---------------------------------------------------------------------------
// Kernel 2b: grid-pruned exact top-16 (R9-verified 4-wave form). One wave per
// query; ring-growing bound check; exact full-scan fallback on candidate
// overflow. (verified on hardware: absmax 6.1e-5)
// ---------------------------------------------------------------------------
__global__ __launch_bounds__(256) void topk_kernel(
    const float* __restrict__ q_coor, const float4* __restrict__ sorted,
    const int* __restrict__ starts, int* __restrict__ idx_out) {
  __shared__ unsigned long long cand[4][CAP];  // 8 KB
  __shared__ int fcnt[4];

  const int tid = threadIdx.x;
  const int wv = tid >> 6;
  const int lane = tid & 63;
  const int qi = blockIdx.x * 4 + wv;  // b*S + s
  const int b = qi >> 12;              // / NS

  const float qx = q_coor[(size_t)qi * 2 + 0];
  const float qy = q_coor[(size_t)qi * 2 + 1];
  const float q2 = sum_sq_np(qx, qy);
  const float4* sp = sorted + (size_t)b * NL;
  const int* st = starts + b * (GCELLS * GCELLS + 1);
  int* outp = idx_out + (size_t)qi * NK;

  int ci = (int)(qx * 32.0f); ci = ci > 31 ? 31 : ci;
  int cj = (int)(qy * 32.0f); cj = cj > 31 ? 31 : cj;

  int x0 = ci - 1 < 0 ? 0 : ci - 1, x1 = ci + 1 > 31 ? 31 : ci + 1;
  int y0 = cj - 1 < 0 ? 0 : cj - 1, y1 = cj + 1 > 31 ? 31 : cj + 1;
  int cnt = 0;
  bool ovf = false;

  auto span = [&](int y, int xa, int xb) {
    int s0 = st[y * GCELLS + xa];
    int e0 = st[y * GCELLS + xb + 1];
    int len = e0 - s0;
    if (cnt + len > CAP) { ovf = true; return; }
    for (int i = lane; i < len; i += 64) {
      float4 rx = sp[s0 + i];
      float d2 = dist2_fast(q2, rx.z, qx, qy, rx.x, rx.y);
      cand[wv][cnt + i] = ((unsigned long long)f32ord(d2) << 32) |
                          (unsigned)__float_as_int(rx.w);
    }
    cnt += len;
  };

  for (int y = y0; y <= y1 && !ovf; ++y) span(y, x0, x1);

  int R = 1;
  while (!ovf) {
    unsigned tau_ord;
    if (cnt <= 128) tau_ord = extract16<2>(cand[wv], cnt, lane, outp);
    else            tau_ord = extract16<4>(cand[wv], cnt, lane, outp);
    float dxl = x0 > 0  ? qx - (float)x0 * GH        : 1e30f;
    float dxr = x1 < 31 ? (float)(x1 + 1) * GH - qx  : 1e30f;
    float dyl = y0 > 0  ? qy - (float)y0 * GH        : 1e30f;
    float dyr = y1 < 31 ? (float)(y1 + 1) * GH - qy  : 1e30f;
    float dmin = fminf(fminf(dxl, dxr), fminf(dyl, dyr));
    float bound = dmin * dmin - EPSM;
    if (cnt >= NK && tau_ord < f32ord(bound)) return;
    if (x0 == 0 && x1 == 31 && y0 == 0 && y1 == 31) return;  // all visited
    ++R;
    int nx0 = ci - R < 0 ? 0 : ci - R, nx1 = ci + R > 31 ? 31 : ci + R;
    int ny0 = cj - R < 0 ? 0 : cj - R, ny1 = cj + R > 31 ? 31 : cj + R;
    if (ny0 < y0) span(ny0, nx0, nx1);
    if (ny1 > y1 && !ovf) span(ny1, nx0, nx1);
    for (int y = y0; y <= y1 && !ovf; ++y) {
      if (nx0 < x0) span(y, nx0, x0 - 1);
      if (nx1 > x1 && !ovf) span(y, x1 + 1, nx1);
    }
    x0 = nx0; x1 = nx1; y0 = ny0; y1 = ny1;
  }

  // ---- exact fallback: full scan over sorted records ----
  float lmin = __builtin_inff();
#pragma unroll 8
  for (int it = 0; it < NL / 64; ++it) {
    float4 rx = sp[it * 64 + lane];
    float d2 = dist2_fast(q2, rx.z, qx, qy, rx.x, rx.y);
    lmin = fminf(lmin, d2);
  }
  float tau;
  {
    float curm = lmin;
    for (int r = 0; r < NK; ++r) {
      float m = curm;
#pragma unroll
      for (int o = 1; o < 64; o <<= 1) m = fminf(m, __shfl_xor(m, o, 64));
      tau = m;
      if (curm == m) curm = __builtin_inff();
    }
  }
  if (lane == 0) fcnt[wv] = 0;
#pragma unroll 4
  for (int it = 0; it < NL / 64; ++it) {
    float4 rx = sp[it * 64 + lane];
    float d2 = dist2_fast(q2, rx.z, qx, qy, rx.x, rx.y);
    bool hit = (d2 <= tau);
    unsigned long long mask = __ballot(hit);
    if (mask) {
      int base = fcnt[wv];
      if (hit) {
        int pos = base + (int)__popcll(mask & ((1ull << lane) - 1ull));
        if (pos < CAP) {
          cand[wv][pos] = ((unsigned long long)f32ord(d2) << 32) |
                          (unsigned)__float_as_int(rx.w);
        }
      }
      if (lane == 0) fcnt[wv] = base + (int)__popcll(mask);
    }
  }
  int N = fcnt[wv];
  if (N > CAP) N = CAP;
  extract16<4>(cand[wv], N, lane, outp);
}

// ---------------------------------------------------------------------------
// Kernel 3 (R14): gather + per-(b,s,k) softmax over D + scale by memory.
// Every (query,k) pair is INDEPENDENT (softmax is over D per (b,s,k)).
// R14 change: one block per query, 4 waves x 4 k's each (was 1 wave x 16 k)
// => 4x the concurrent gather chains, serial chain per wave 16 -> 4, for
// latency hiding. Cell-sorted qord + XCD swizzle retained (consecutive
// blocks in a swizzle chunk = consecutive sorted queries). Per-(qi,k)
// arithmetic and output rows unchanged => bit-identical.
// ---------------------------------------------------------------------------
__global__ __launch_bounds__(256) void attn_kernel(
    const float* __restrict__ query, const float* __restrict__ kv_pe,
    const float* __restrict__ memory, const int* __restrict__ idx,
    const int* __restrict__ qord, float* __restrict__ out) {
  const int tid = threadIdx.x;
  const int wv = tid >> 6;
  const int lane = tid & 63;
  // XCD swizzle: 16384 blocks, bijective (16384 % 8 == 0)
  const int bid = ((blockIdx.x & 7) * (NB * NS / 8)) + (blockIdx.x >> 3);
  const int qpos = bid;                // position in sorted order
  const int b = qpos >> 12;            // / NS
  const int qi = b * NS + qord[qpos];  // original b*S + s

  float4 q4 = *(const float4*)(query + (size_t)qi * ND + lane * 4);
  int lv = 0;
  if (lane < 4) lv = idx[(size_t)qi * NK + wv * 4 + lane];

#pragma unroll
  for (int j = 0; j < 4; ++j) {
    int k = wv * 4 + j;
    int l = __shfl(lv, j, 64);
    size_t base = ((size_t)b * NL + l) * ND + (size_t)lane * 4;
    float4 kv = *(const float4*)(kv_pe + base);
    float4 mm = *(const float4*)(memory + base);
    // prod = query * kv_pe / sqrt(256); /16 is exact so *0.0625f matches bits
    float p0 = q4.x * kv.x * 0.0625f;
    float p1 = q4.y * kv.y * 0.0625f;
    float p2 = q4.z * kv.z * 0.0625f;
    float p3 = q4.w * kv.w * 0.0625f;
    float mx = fmaxf(fmaxf(p0, p1), fmaxf(p2, p3));
#pragma unroll
    for (int o = 1; o < 64; o <<= 1) mx = fmaxf(mx, __shfl_xor(mx, o, 64));
    float e0 = expf(p0 - mx);
    float e1 = expf(p1 - mx);
    float e2 = expf(p2 - mx);
    float e3 = expf(p3 - mx);
    float s = (e0 + e1) + (e2 + e3);
#pragma unroll
    for (int o = 1; o < 64; o <<= 1) s += __shfl_xor(s, o, 64);
    float inv = 1.0f / s;
    float4 o4;
    o4.x = e0 * inv * mm.x;
    o4.y = e1 * inv * mm.y;
    o4.z = e2 * inv * mm.z;
    o4.w = e3 * inv * mm.w;
    *(float4*)(out + ((size_t)qi * NK + k) * ND + (size_t)lane * 4) = o4;
  }
}

// ---------------------------------------------------------------------------
extern "C" void kernel_launch(void* const* d_in, const int* in_sizes, int n_in,
                              void* d_out, int out_size, void* d_ws, size_t ws_size,
                              hipStream_t stream) {
  (void)in_sizes; (void)n_in; (void)out_size; (void)ws_size;
  const float* memory   = (const float*)d_in[0];
  const float* mem_coor = (const float*)d_in[1];
  const float* q_coor   = (const float*)d_in[2];
  const float* Wq1 = (const float*)d_in[3];
  const float* bq1 = (const float*)d_in[4];
  const float* Wq2 = (const float*)d_in[5];
  const float* bq2 = (const float*)d_in[6];
  const float* Wk1 = (const float*)d_in[7];
  const float* bk1 = (const float*)d_in[8];
  const float* Wk2 = (const float*)d_in[9];
  const float* bk2 = (const float*)d_in[10];

  // workspace: query (16.8 MB) | kv_pe (33.6 MB) | idx (1 MB) | qord (64 KB)
  float* query = (float*)d_ws;
  float* kv_pe = query + (size_t)NB * NS * ND;
  int*   nidx  = (int*)(kv_pe + (size_t)NB * NL * ND);
  int*   qord  = nidx + (size_t)NB * NS * NK;
  float* outp  = (float*)d_out;

  // grid scratch lives in d_out (268 MB): consumed by topk (stream-ordered
  // before attn overwrites the buffer). qord lives in d_ws (attn reads it
  // while writing out).
  float4* sorted  = (float4*)d_out;                                  // 512 KB
  int*    gstarts = (int*)((char*)d_out + (size_t)NB * NL * 16);     // 16.4 KB

  hipLaunchKernelGGL(build_kernel, dim3(2 * NB), dim3(1024), 0, stream,
                     mem_coor, q_coor, sorted, gstarts, qord);
  hipLaunchKernelGGL(mlp_fused_kernel, dim3(NSBLK + NB * NL / 16), dim3(64),
                     0, stream, q_coor, mem_coor, memory,
                     Wq1, bq1, Wq2, bq2, Wk1, bk1, Wk2, bk2, query, kv_pe);
  hipLaunchKernelGGL(topk_kernel, dim3(NB * NS / 4), dim3(256), 0, stream,
                     q_coor, sorted, gstarts, nidx);
  hipLaunchKernelGGL(attn_kernel, dim3(NB * NS), dim3(256), 0, stream,
                     query, kv_pe, memory, nidx, qord, outp);
}

// Round 17
// 500.391 us; speedup vs baseline: 1.1408x; 1.0524x over previous
//
#include <hip/hip_runtime.h>
#include <math.h>

// Problem constants (fixed by setup_inputs)
#define NB 4
#define NS 4096
#define NL 8192
#define ND 256
#define NP2 128
#define NK 16

// Grid for spatial top-k pruning
#define GCELLS 32
#define GH 0.03125f     // 1/32, exact power of two
#define CAP 256         // per-wave candidate cap (overflow -> exact fallback)
#define EPSM 2e-5f      // skip margin >> 3e-6 total fp error of ref d2 chain

// ---------------------------------------------------------------------------
// Reference-matching fp32 distance metric (XLA/BLAS k=2 GEMM model) — VERIFIED
// on hardware through R14 (absmax 6.1e-5). DO NOT CHANGE THE BITS.
// ---------------------------------------------------------------------------
__device__ __forceinline__ float sum_sq_np(float x, float y) {
#pragma clang fp contract(off)
  return x * x + y * y;
}

__device__ __forceinline__ float dist2_fast(float q2, float m2, float qx, float qy,
                                            float mx, float my) {
#pragma clang fp contract(off)
  float dot = __builtin_fmaf(qy, my, qx * mx);
  float s = q2 + m2;
  return __builtin_fmaf(-2.0f, dot, s);
}

// float -> order-preserving uint (ascending float => ascending uint)
__device__ __forceinline__ unsigned f32ord(float f) {
  unsigned u = __float_as_uint(f);
  return u ^ ((unsigned)((int)u >> 31) | 0x80000000u);
}

// 16 rounds of wave-wide u64 min-extract over cand[0..cnt) (d2 asc, ties idx
// asc — exactly jax.lax.top_k's lower-index tie rule). Winning key is wave-
// uniform after the reduce; lane 0 stores its index into idxsel (LDS).
template <int NR>
__device__ __forceinline__ unsigned extract16(const unsigned long long* candrow,
                                              int cnt, int lane,
                                              int* __restrict__ idxsel) {
  unsigned long long myc[NR];
#pragma unroll
  for (int j = 0; j < NR; ++j) {
    int p = lane + j * 64;
    myc[j] = (p < cnt) ? candrow[p] : ~0ull;
  }
  unsigned tau_ord = 0xffffffffu;
#pragma unroll 1
  for (int r = 0; r < NK; ++r) {
    unsigned long long m = myc[0];
#pragma unroll
    for (int j = 1; j < NR; ++j) m = myc[j] < m ? myc[j] : m;
#pragma unroll
    for (int o = 1; o < 64; o <<= 1) {
      unsigned long long other = __shfl_xor(m, o, 64);
      if (other < m) m = other;
    }
    if (lane == 0) idxsel[r] = (int)(unsigned)(m & 0xffffffffull);
    if (r == NK - 1) tau_ord = (unsigned)(m >> 32);
#pragma unroll
    for (int j = 0; j < NR; ++j)
      if (myc[j] == m) myc[j] = ~0ull;
  }
  return tau_ord;
}

// ---------------------------------------------------------------------------
// Kernel 1 (R12-verified): fused S+L MLP, 64 thr (1 wave), 16 rows/block,
// FOUR cols per thread (c0 = 4*tid). FMA:LDS-read ratio 16:1; W loads/stores
// float4 coalesced. pe/h LDS union (20480 B). NO min-waves clause (R8 spill
// lesson); NO r-split (R13: +37 us). Occupancy measured pinned ~18-20%
// across all LDS sizes/shapes — do not chase it further. 152 us class.
// ---------------------------------------------------------------------------
#define RPAD 20
#define NSBLK (NB * NS / 16)  // 1024 S-instance blocks; total 3072

struct __align__(16) MlpSmem {
  union {
    float pe[NP2][RPAD];  // 10.24 KB, live phase1 -> end of phase2 k-loop
    float h[ND][RPAD];    // 20.48 KB, live after barrier -> end of phase3
  };
};

__device__ __forceinline__ void fma4row(float4& a, float p, const float4& w) {
  a.x = fmaf(p, w.x, a.x);
  a.y = fmaf(p, w.y, a.y);
  a.z = fmaf(p, w.z, a.z);
  a.w = fmaf(p, w.w, a.w);
}

// 4 k-steps: per k, read pe/h row (16 floats, broadcast) and do 16x4 FMAs.
__device__ __forceinline__ void consume4v(const float (*L)[RPAD], int k0,
                                          const float4* w, float4* acc) {
#pragma unroll
  for (int u = 0; u < 4; ++u) {
    int k = k0 + u;
    float4 p0 = *(const float4*)&L[k][0];
    float4 p1 = *(const float4*)&L[k][4];
    float4 p2 = *(const float4*)&L[k][8];
    float4 p3 = *(const float4*)&L[k][12];
    float4 wu = w[u];
    fma4row(acc[0],  p0.x, wu); fma4row(acc[1],  p0.y, wu);
    fma4row(acc[2],  p0.z, wu); fma4row(acc[3],  p0.w, wu);
    fma4row(acc[4],  p1.x, wu); fma4row(acc[5],  p1.y, wu);
    fma4row(acc[6],  p1.z, wu); fma4row(acc[7],  p1.w, wu);
    fma4row(acc[8],  p2.x, wu); fma4row(acc[9],  p2.y, wu);
    fma4row(acc[10], p2.z, wu); fma4row(acc[11], p2.w, wu);
    fma4row(acc[12], p3.x, wu); fma4row(acc[13], p3.y, wu);
    fma4row(acc[14], p3.z, wu); fma4row(acc[15], p3.w, wu);
  }
}

__global__ __launch_bounds__(64) void mlp_fused_kernel(
    const float* __restrict__ q_coor, const float* __restrict__ mem_coor,
    const float* __restrict__ memory,
    const float* __restrict__ Wq1, const float* __restrict__ bq1,
    const float* __restrict__ Wq2, const float* __restrict__ bq2,
    const float* __restrict__ Wk1, const float* __restrict__ bk1,
    const float* __restrict__ Wk2, const float* __restrict__ bk2,
    float* __restrict__ query, float* __restrict__ kv_pe) {
  __shared__ MlpSmem sm;
  const int tid = threadIdx.x;   // 0..63
  const int bid = blockIdx.x;
  const bool isS = bid < NSBLK;
  const float* coor = isS ? q_coor : mem_coor;
  const float* W1 = isS ? Wq1 : Wk1;
  const float* b1 = isS ? bq1 : bk1;
  const float* W2 = isS ? Wq2 : Wk2;
  const float* b2 = isS ? bq2 : bk2;
  const float* addmem = isS ? (const float*)nullptr : memory;
  float* out = isS ? query : kv_pe;
  const int row0 = (isS ? bid : bid - NSBLK) * 16;
  const int c0 = tid * 4;

  // ---- phase 1: PETR 2D sine embedding, transposed into LDS ----
#pragma unroll
  for (int it = 0; it < 16; ++it) {
    int e = tid + it * 64;      // 0..1023 = 16 rows * 2 parts * 32 j
    int r = e >> 6;
    int rem = e & 63;
    int part = rem >> 5;        // 0 -> y, 1 -> x
    int j = rem & 31;
    float c = coor[(size_t)(row0 + r) * 2 + (part ^ 1)];
    float inv_t = exp2f((float)j * -0.4152410118609718f);  // 10000^(-j/32)
    float arg = c * 6.2831853071795864f * inv_t;
    float sv, cv;
    sincosf(arg, &sv, &cv);
    int k0 = part * 64 + 2 * j;
    sm.pe[k0][r] = sv;
    sm.pe[k0 + 1][r] = cv;
  }
  __syncthreads();

  // ---- phase 2: hidden = relu(pe @ W1 + b1), 4-deep double-buffered W ----
  float4 acc[16];
  float4 wA[4], wB[4];
  {
    float4 bb = *(const float4*)&b1[c0];
#pragma unroll
    for (int r = 0; r < 16; ++r) acc[r] = bb;
  }
#pragma unroll
  for (int u = 0; u < 4; ++u)
    wA[u] = *(const float4*)&W1[(size_t)u * ND + c0];
#pragma unroll 1
  for (int k0 = 0; k0 < NP2; k0 += 8) {
#pragma unroll
    for (int u = 0; u < 4; ++u)
      wB[u] = *(const float4*)&W1[(size_t)(k0 + 4 + u) * ND + c0];
    consume4v(sm.pe, k0, wA, acc);
    if (k0 + 8 < NP2) {
#pragma unroll
      for (int u = 0; u < 4; ++u)
        wA[u] = *(const float4*)&W1[(size_t)(k0 + 8 + u) * ND + c0];
    }
    consume4v(sm.pe, k0 + 4, wB, acc);
  }
  __syncthreads();  // all pe reads complete before h overwrites union
  // thread owns hidden cols c0..c0+3: h[c][r] = relu(acc[r].comp(c-c0))
#pragma unroll
  for (int r = 0; r < 16; ++r) {
    sm.h[c0 + 0][r] = fmaxf(acc[r].x, 0.0f);
    sm.h[c0 + 1][r] = fmaxf(acc[r].y, 0.0f);
    sm.h[c0 + 2][r] = fmaxf(acc[r].z, 0.0f);
    sm.h[c0 + 3][r] = fmaxf(acc[r].w, 0.0f);
  }
  __syncthreads();

  // ---- phase 3: out = h @ W2 + b2 (+ memory), same structure, K=256 ----
  {
    float4 bb = *(const float4*)&b2[c0];
#pragma unroll
    for (int r = 0; r < 16; ++r) acc[r] = bb;
  }
#pragma unroll
  for (int u = 0; u < 4; ++u)
    wA[u] = *(const float4*)&W2[(size_t)u * ND + c0];
#pragma unroll 1
  for (int k0 = 0; k0 < ND; k0 += 8) {
#pragma unroll
    for (int u = 0; u < 4; ++u)
      wB[u] = *(const float4*)&W2[(size_t)(k0 + 4 + u) * ND + c0];
    consume4v(sm.h, k0, wA, acc);
    if (k0 + 8 < ND) {
#pragma unroll
      for (int u = 0; u < 4; ++u)
        wA[u] = *(const float4*)&W2[(size_t)(k0 + 8 + u) * ND + c0];
    }
    consume4v(sm.h, k0 + 4, wB, acc);
  }
#pragma unroll
  for (int r = 0; r < 16; ++r) {
    size_t g = (size_t)(row0 + r);
    float4 v = acc[r];
    if (addmem) {
      float4 mm = *(const float4*)&addmem[g * ND + c0];
      v.x += mm.x; v.y += mm.y; v.z += mm.z; v.w += mm.w;
    }
    *(float4*)&out[g * ND + c0] = v;
  }
}

// ---------------------------------------------------------------------------
// Kernel 2a: fused build. Blocks [0,NB): counting-sort mem points into cell
// order (sorted records + starts). Blocks [NB,2*NB): counting-sort the
// QUERIES by cell -> qord, used by topk_attn for gather locality. (verified)
// ---------------------------------------------------------------------------
__global__ __launch_bounds__(1024) void build_kernel(
    const float* __restrict__ mem_coor, const float* __restrict__ q_coor,
    float4* __restrict__ sorted, int* __restrict__ starts,
    int* __restrict__ qord) {
  __shared__ int hist[GCELLS * GCELLS];
  __shared__ int cur[GCELLS * GCELLS];
  const int bid = blockIdx.x;
  const bool isMem = bid < NB;
  const int b = isMem ? bid : bid - NB;
  const int n = isMem ? NL : NS;
  const float2* cc = (const float2*)(isMem ? mem_coor : q_coor) + (size_t)b * n;
  const int tid = threadIdx.x;

  hist[tid] = 0;
  __syncthreads();
  for (int it = 0; it < n / 1024; ++it) {
    float2 c = cc[it * 1024 + tid];
    int cx = (int)(c.x * 32.0f); cx = cx > 31 ? 31 : cx;
    int cy = (int)(c.y * 32.0f); cy = cy > 31 ? 31 : cy;
    atomicAdd(&hist[cy * GCELLS + cx], 1);
  }
  __syncthreads();
  const int own = hist[tid];
  for (int o = 1; o < 1024; o <<= 1) {
    int v = (tid >= o) ? hist[tid - o] : 0;
    __syncthreads();
    hist[tid] += v;
    __syncthreads();
  }
  const int excl = hist[tid] - own;
  if (isMem) {
    starts[b * (GCELLS * GCELLS + 1) + tid] = excl;
    if (tid == 0) starts[b * (GCELLS * GCELLS + 1) + GCELLS * GCELLS] = NL;
  }
  cur[tid] = excl;
  __syncthreads();
  for (int it = 0; it < n / 1024; ++it) {
    int i = it * 1024 + tid;
    float2 c = cc[i];
    int cx = (int)(c.x * 32.0f); cx = cx > 31 ? 31 : cx;
    int cy = (int)(c.y * 32.0f); cy = cy > 31 ? 31 : cy;
    int pos = atomicAdd(&cur[cy * GCELLS + cx], 1);
    if (isMem) {
      sorted[(size_t)b * NL + pos] =
          make_float4(c.x, c.y, sum_sq_np(c.x, c.y), __int_as_float(i));
    } else {
      qord[b * NS + pos] = i;
    }
  }
}

// ---------------------------------------------------------------------------
// Kernel 2b (R15): FUSED topk+attn. One wave per query (4 waves/block),
// queries in cell-sorted order (qord) + XCD swizzle. Per wave:
//   phase A: grid-pruned exact top-16 (R9-verified logic verbatim; ring-
//            growing bound check; exact full-scan fallback on overflow).
//            Selected indices land in idxsel[wv][16] (LDS, 256 B).
//   phase B: R12-verified attn 16-k loop, reading idx from LDS instead of
//            global (same values, same order => bit-identical).
// Rationale: attn depends only on the SAME query's idx. Fusing lets one
// wave's VMEM-latency-bound attn overlap other waves' VALU-bound topk, kills
// the nidx round-trip and one dispatch, and gives topk the sorted-locality
// win too. No cross-wave barriers (all state per-wave).
// ---------------------------------------------------------------------------
__global__ __launch_bounds__(256) void topk_attn_kernel(
    const float* __restrict__ q_coor, const float4* __restrict__ sorted,
    const int* __restrict__ starts, const int* __restrict__ qord,
    const float* __restrict__ query, const float* __restrict__ kv_pe,
    const float* __restrict__ memory, float* __restrict__ out) {
  __shared__ unsigned long long cand[4][CAP];  // 8 KB
  __shared__ int fcnt[4];
  __shared__ int idxsel[4][NK];                // 256 B

  const int tid = threadIdx.x;
  const int wv = tid >> 6;
  const int lane = tid & 63;
  // XCD swizzle: 4096 blocks, bijective (4096 % 8 == 0)
  const int bid = ((blockIdx.x & 7) * (NB * NS / 4 / 8)) + (blockIdx.x >> 3);
  const int qpos = bid * 4 + wv;       // position in sorted order
  const int b = qpos >> 12;            // / NS
  const int qi = b * NS + qord[qpos];  // original b*S + s

  // ================= phase A: exact top-16 =================
  const float qx = q_coor[(size_t)qi * 2 + 0];
  const float qy = q_coor[(size_t)qi * 2 + 1];
  const float q2 = sum_sq_np(qx, qy);
  const float4* sp = sorted + (size_t)b * NL;
  const int* st = starts + b * (GCELLS * GCELLS + 1);
  int* isel = idxsel[wv];

  int ci = (int)(qx * 32.0f); ci = ci > 31 ? 31 : ci;
  int cj = (int)(qy * 32.0f); cj = cj > 31 ? 31 : cj;

  int x0 = ci - 1 < 0 ? 0 : ci - 1, x1 = ci + 1 > 31 ? 31 : ci + 1;
  int y0 = cj - 1 < 0 ? 0 : cj - 1, y1 = cj + 1 > 31 ? 31 : cj + 1;
  int cnt = 0;
  bool ovf = false;

  auto span = [&](int y, int xa, int xb) {
    int s0 = st[y * GCELLS + xa];
    int e0 = st[y * GCELLS + xb + 1];
    int len = e0 - s0;
    if (cnt + len > CAP) { ovf = true; return; }
    for (int i = lane; i < len; i += 64) {
      float4 rx = sp[s0 + i];
      float d2 = dist2_fast(q2, rx.z, qx, qy, rx.x, rx.y);
      cand[wv][cnt + i] = ((unsigned long long)f32ord(d2) << 32) |
                          (unsigned)__float_as_int(rx.w);
    }
    cnt += len;
  };

  for (int y = y0; y <= y1 && !ovf; ++y) span(y, x0, x1);

  bool done = false;
  int R = 1;
  while (!ovf && !done) {
    unsigned tau_ord;
    if (cnt <= 128) tau_ord = extract16<2>(cand[wv], cnt, lane, isel);
    else            tau_ord = extract16<4>(cand[wv], cnt, lane, isel);
    float dxl = x0 > 0  ? qx - (float)x0 * GH        : 1e30f;
    float dxr = x1 < 31 ? (float)(x1 + 1) * GH - qx  : 1e30f;
    float dyl = y0 > 0  ? qy - (float)y0 * GH        : 1e30f;
    float dyr = y1 < 31 ? (float)(y1 + 1) * GH - qy  : 1e30f;
    float dmin = fminf(fminf(dxl, dxr), fminf(dyl, dyr));
    float bound = dmin * dmin - EPSM;
    if (cnt >= NK && tau_ord < f32ord(bound)) { done = true; break; }
    if (x0 == 0 && x1 == 31 && y0 == 0 && y1 == 31) { done = true; break; }
    ++R;
    int nx0 = ci - R < 0 ? 0 : ci - R, nx1 = ci + R > 31 ? 31 : ci + R;
    int ny0 = cj - R < 0 ? 0 : cj - R, ny1 = cj + R > 31 ? 31 : cj + R;
    if (ny0 < y0) span(ny0, nx0, nx1);
    if (ny1 > y1 && !ovf) span(ny1, nx0, nx1);
    for (int y = y0; y <= y1 && !ovf; ++y) {
      if (nx0 < x0) span(y, nx0, x0 - 1);
      if (nx1 > x1 && !ovf) span(y, x1 + 1, nx1);
    }
    x0 = nx0; x1 = nx1; y0 = ny0; y1 = ny1;
  }

  if (!done) {
    // ---- exact fallback: full scan over sorted records ----
    float lmin = __builtin_inff();
#pragma unroll 8
    for (int it = 0; it < NL / 64; ++it) {
      float4 rx = sp[it * 64 + lane];
      float d2 = dist2_fast(q2, rx.z, qx, qy, rx.x, rx.y);
      lmin = fminf(lmin, d2);
    }
    float tau;
    {
      float curm = lmin;
      for (int r = 0; r < NK; ++r) {
        float m = curm;
#pragma unroll
        for (int o = 1; o < 64; o <<= 1) m = fminf(m, __shfl_xor(m, o, 64));
        tau = m;
        if (curm == m) curm = __builtin_inff();
      }
    }
    if (lane == 0) fcnt[wv] = 0;
#pragma unroll 4
    for (int it = 0; it < NL / 64; ++it) {
      float4 rx = sp[it * 64 + lane];
      float d2 = dist2_fast(q2, rx.z, qx, qy, rx.x, rx.y);
      bool hit = (d2 <= tau);
      unsigned long long mask = __ballot(hit);
      if (mask) {
        int base = fcnt[wv];
        if (hit) {
          int pos = base + (int)__popcll(mask & ((1ull << lane) - 1ull));
          if (pos < CAP) {
            cand[wv][pos] = ((unsigned long long)f32ord(d2) << 32) |
                            (unsigned)__float_as_int(rx.w);
          }
        }
        if (lane == 0) fcnt[wv] = base + (int)__popcll(mask);
      }
    }
    int N = fcnt[wv];
    if (N > CAP) N = CAP;
    extract16<4>(cand[wv], N, lane, isel);
  }

  // ================= phase B: attn (R12-verified loop) =================
  float4 q4 = *(const float4*)(query + (size_t)qi * ND + lane * 4);

#pragma unroll 4
  for (int k = 0; k < NK; ++k) {
    int l = isel[k];  // LDS broadcast, wave-uniform
    size_t base = ((size_t)b * NL + l) * ND + (size_t)lane * 4;
    float4 kv = *(const float4*)(kv_pe + base);
    float4 mm = *(const float4*)(memory + base);
    // prod = query * kv_pe / sqrt(256); /16 is exact so *0.0625f matches bits
    float p0 = q4.x * kv.x * 0.0625f;
    float p1 = q4.y * kv.y * 0.0625f;
    float p2 = q4.z * kv.z * 0.0625f;
    float p3 = q4.w * kv.w * 0.0625f;
    float mx = fmaxf(fmaxf(p0, p1), fmaxf(p2, p3));
#pragma unroll
    for (int o = 1; o < 64; o <<= 1) mx = fmaxf(mx, __shfl_xor(mx, o, 64));
    float e0 = expf(p0 - mx);
    float e1 = expf(p1 - mx);
    float e2 = expf(p2 - mx);
    float e3 = expf(p3 - mx);
    float s = (e0 + e1) + (e2 + e3);
#pragma unroll
    for (int o = 1; o < 64; o <<= 1) s += __shfl_xor(s, o, 64);
    float inv = 1.0f / s;
    float4 o4;
    o4.x = e0 * inv * mm.x;
    o4.y = e1 * inv * mm.y;
    o4.z = e2 * inv * mm.z;
    o4.w = e3 * inv * mm.w;
    *(float4*)(out + ((size_t)qi * NK + k) * ND + (size_t)lane * 4) = o4;
  }
}

// ---------------------------------------------------------------------------
extern "C" void kernel_launch(void* const* d_in, const int* in_sizes, int n_in,
                              void* d_out, int out_size, void* d_ws, size_t ws_size,
                              hipStream_t stream) {
  (void)in_sizes; (void)n_in; (void)out_size; (void)ws_size;
  const float* memory   = (const float*)d_in[0];
  const float* mem_coor = (const float*)d_in[1];
  const float* q_coor   = (const float*)d_in[2];
  const float* Wq1 = (const float*)d_in[3];
  const float* bq1 = (const float*)d_in[4];
  const float* Wq2 = (const float*)d_in[5];
  const float* bq2 = (const float*)d_in[6];
  const float* Wk1 = (const float*)d_in[7];
  const float* bk1 = (const float*)d_in[8];
  const float* Wk2 = (const float*)d_in[9];
  const float* bk2 = (const float*)d_in[10];

  // workspace: query (16.8 MB) | kv_pe (33.6 MB) | qord (64 KB)
  float* query = (float*)d_ws;
  float* kv_pe = query + (size_t)NB * NS * ND;
  int*   qord  = (int*)(kv_pe + (size_t)NB * NL * ND);
  float* outp  = (float*)d_out;

  // grid scratch (sorted/starts) lives in d_ws slack after qord — NOT in
  // d_out, because topk_attn's phase B writes out[] while phase A of other
  // blocks still reads the grid structures (no cross-block ordering).
  float4* sorted  = (float4*)(qord + NB * NS);
  int*    gstarts = (int*)(sorted + (size_t)NB * NL);

  hipLaunchKernelGGL(build_kernel, dim3(2 * NB), dim3(1024), 0, stream,
                     mem_coor, q_coor, sorted, gstarts, qord);
  hipLaunchKernelGGL(mlp_fused_kernel, dim3(NSBLK + NB * NL / 16), dim3(64),
                     0, stream, q_coor, mem_coor, memory,
                     Wq1, bq1, Wq2, bq2, Wk1, bk1, Wk2, bk2, query, kv_pe);
  hipLaunchKernelGGL(topk_attn_kernel, dim3(NB * NS / 4), dim3(256), 0,
                     stream, q_coor, sorted, gstarts, qord,
                     query, kv_pe, memory, outp);
}